// Round 1
// baseline (15.424 us; speedup 1.0000x reference)
//
#include <hip/hip_runtime.h>
#include <math.h>

#define NFEAT 10
#define D 160
#define KDIM 32
#define EXB 32          // examples per block
#define BLOCK 256

__global__ __launch_bounds__(BLOCK) void fm_kernel(
    const int* __restrict__ inputs,
    const float* __restrict__ user_table,
    const float* __restrict__ item_table,
    const float* __restrict__ feat_tables,
    const float* __restrict__ w,
    const float* __restrict__ bb,
    const float* __restrict__ k_mat,
    float* __restrict__ out)
{
    __shared__ float x_lds[EXB][D];     // 20 KB gathered features (f32)
    __shared__ float kk2_lds[D];        // sum_k K[d][k]^2

    const int tid   = threadIdx.x;
    const int ebase = blockIdx.x * EXB;

    // ---- stage x: gather 32 examples x 10 features x 16 floats (as float4) ----
    for (int i = tid; i < EXB * 40; i += BLOCK) {
        int e  = i / 40;
        int r  = i - e * 40;        // float4 index within the 160-float row
        int f  = r >> 2;            // feature 0..9
        int j4 = r & 3;             // float4 within the 16-float embedding
        int idx = inputs[(ebase + e) * NFEAT + f];
        const float* src;
        if (f == 0)      src = user_table + (size_t)idx * 16;
        else if (f == 1) src = item_table + (size_t)idx * 16;
        else             src = feat_tables + ((size_t)(f - 2) * 10000 + (size_t)idx) * 16;
        float4 v = *(const float4*)(src + j4 * 4);
        *(float4*)&x_lds[e][r * 4] = v;
    }

    // ---- kk2[d] = sum_k K[d][k]^2 (once per block) ----
    if (tid < D) {
        float acc = 0.f;
        #pragma unroll
        for (int kk = 0; kk < KDIM; ++kk) {
            float kv = k_mat[tid * KDIM + kk];
            acc = fmaf(kv, kv, acc);
        }
        kk2_lds[tid] = acc;
    }
    __syncthreads();

    // ---- compute: wave = 2 examples x 32 k-lanes; each wave does 4 pairs ----
    const int lane = tid & 63;
    const int wid  = tid >> 6;
    const int half = lane >> 5;
    const int k    = lane & 31;

    float s [4] = {0.f, 0.f, 0.f, 0.f};   // s_k partial (x . K[:,k])
    float lt[4] = {0.f, 0.f, 0.f, 0.f};   // lane-distributed linear partial
    float tq[4] = {0.f, 0.f, 0.f, 0.f};   // lane-distributed x^2 . kk2 partial

    for (int c = 0; c < 5; ++c) {
        // K chunk into registers: Kc[j] = K[c*32+j][k] (coalesced across lanes)
        float Kc[32];
        #pragma unroll
        for (int j = 0; j < 32; ++j)
            Kc[j] = k_mat[(c * 32 + j) * KDIM + k];
        float wk = w[c * 32 + k];
        float q2 = kk2_lds[c * 32 + k];

        #pragma unroll
        for (int p = 0; p < 4; ++p) {
            int e = wid * 8 + p * 2 + half;
            const float4* xr = (const float4*)&x_lds[e][c * 32];
            float xv[32];
            #pragma unroll
            for (int u = 0; u < 8; ++u) {
                float4 v4 = xr[u];
                xv[u * 4 + 0] = v4.x; xv[u * 4 + 1] = v4.y;
                xv[u * 4 + 2] = v4.z; xv[u * 4 + 3] = v4.w;
            }
            #pragma unroll
            for (int j = 0; j < 32; ++j)
                s[p] = fmaf(xv[j], Kc[j], s[p]);

            float xk = x_lds[e][c * 32 + k];      // per-lane element for lin/t
            lt[p] = fmaf(xk, wk, lt[p]);
            tq[p] = fmaf(xk * xk, q2, tq[p]);
        }
    }

    // ---- epilogue: v = 0.5*(s^2 - t) + lin, reduce over 32 k-lanes, sigmoid ----
    float bval = bb[0];
    #pragma unroll
    for (int p = 0; p < 4; ++p) {
        float v = 0.5f * (s[p] * s[p] - tq[p]) + lt[p];
        #pragma unroll
        for (int m = 1; m <= 16; m <<= 1)
            v += __shfl_xor(v, m, 64);
        if (k == 0) {
            int e = ebase + wid * 8 + p * 2 + half;
            out[e] = 1.0f / (1.0f + __expf(-(v + bval)));
        }
    }
}

extern "C" void kernel_launch(void* const* d_in, const int* in_sizes, int n_in,
                              void* d_out, int out_size, void* d_ws, size_t ws_size,
                              hipStream_t stream) {
    const int*   inputs      = (const int*)  d_in[0];
    const float* user_table  = (const float*)d_in[1];
    const float* item_table  = (const float*)d_in[2];
    const float* feat_tables = (const float*)d_in[3];
    const float* w           = (const float*)d_in[4];
    const float* b           = (const float*)d_in[5];
    const float* k_mat       = (const float*)d_in[6];
    float* out = (float*)d_out;

    int nblocks = out_size / EXB;   // 16384 / 32 = 512
    fm_kernel<<<nblocks, BLOCK, 0, stream>>>(inputs, user_table, item_table,
                                             feat_tables, w, b, k_mat, out);
}